// Round 3
// baseline (5381.639 us; speedup 1.0000x reference)
//
#include <hip/hip_runtime.h>
#include <stdint.h>

#define BATCH 2
#define TSEQ  2048
#define CDIM  2048
#define NHEAD 16
#define NKV   4
#define HDIM  128
#define KVDIM 512   /* NKV*HDIM */
#define WIN   1024
#define SINKN 4
#define MAXKEYS 1056  /* >= SINKN + WIN + 1 = 1029 */

__device__ __forceinline__ float bf2f(unsigned short u) {
  union { uint32_t i; float f; } w; w.i = ((uint32_t)u) << 16; return w.f;
}
__device__ __forceinline__ unsigned short f2bf(float f) {
  union { uint32_t i; float f; } w; w.f = f;
  return (unsigned short)((w.i + 0x7fffu + ((w.i >> 16) & 1u)) >> 16);
}

// Decide whether input tensors are f32 (flag=0) or packed bf16 (flag=1).
// Looks at the bf16-exponent field of the LOW 16 bits of the first 1024
// 32-bit words of x: bf16-packed -> N(0,1) exponents cluster in [100,135]
// (~100% hit); f32 -> those bits are mantissa, uniform (~14% hit).
__global__ __launch_bounds__(256)
void detect_kernel(const uint32_t* __restrict__ x, uint32_t* __restrict__ flag) {
  __shared__ int red[4];
  const int tid = threadIdx.x;
  int c = 0;
  for (int i = tid; i < 1024; i += 256) {
    uint32_t e = (x[i] >> 7) & 0xFFu;
    c += (e >= 100u && e <= 135u) ? 1 : 0;
  }
#pragma unroll
  for (int off = 32; off; off >>= 1) c += __shfl_xor(c, off, 64);
  if ((tid & 63) == 0) red[tid >> 6] = c;
  __syncthreads();
  if (tid == 0) flag[0] = ((red[0] + red[1] + red[2] + red[3]) > 512) ? 1u : 0u;
}

// Normalize an input tensor to canonical bf16 (ushort). Never reads beyond
// the smaller interpretation unless the flag proves the buffer is f32.
__global__ __launch_bounds__(256)
void convert_kernel(const void* __restrict__ src, unsigned short* __restrict__ dst,
                    int n, const uint32_t* __restrict__ flag) {
  const int i = blockIdx.x * 256 + threadIdx.x;
  if (i >= n) return;
  if (flag[0]) dst[i] = ((const unsigned short*)src)[i];
  else         dst[i] = f2bf(((const float*)src)[i]);
}

// C[M,N] = A[M,K] * B[K,N]; bf16 in, f32 accumulate.
// Store: ushort (flagp==nullptr or *flagp==1) or float (*flagp==0).
// 64x64 tile, 256 threads, 4x4 per thread, BK=16.
__global__ __launch_bounds__(256)
void gemm_bf16(const unsigned short* __restrict__ A,
               const unsigned short* __restrict__ B,
               void* __restrict__ C,
               int M, int N, int K, const uint32_t* __restrict__ flagp) {
  __shared__ float As[16][65];
  __shared__ float Bs[16][65];
  const int tid = threadIdx.x;
  const int tx = tid & 15, ty = tid >> 4;
  const int m0 = blockIdx.y * 64, n0 = blockIdx.x * 64;
  float acc[4][4] = {};
  const int ar = tid >> 2, ac = (tid & 3) << 2;   // A: row 0..63, col {0,4,8,12}
  const int bk = tid >> 4, bc = (tid & 15) << 2;  // B: k 0..15, col {0,4,...,60}
  for (int k0 = 0; k0 < K; k0 += 16) {
    ushort4 a4 = *(const ushort4*)(A + (size_t)(m0 + ar) * K + k0 + ac);
    ushort4 b4 = *(const ushort4*)(B + (size_t)(k0 + bk) * N + n0 + bc);
    As[ac + 0][ar] = bf2f(a4.x);
    As[ac + 1][ar] = bf2f(a4.y);
    As[ac + 2][ar] = bf2f(a4.z);
    As[ac + 3][ar] = bf2f(a4.w);
    Bs[bk][bc + 0] = bf2f(b4.x);
    Bs[bk][bc + 1] = bf2f(b4.y);
    Bs[bk][bc + 2] = bf2f(b4.z);
    Bs[bk][bc + 3] = bf2f(b4.w);
    __syncthreads();
#pragma unroll
    for (int kk = 0; kk < 16; ++kk) {
      float a[4], b[4];
#pragma unroll
      for (int i = 0; i < 4; ++i) a[i] = As[kk][ty + 16 * i];
#pragma unroll
      for (int j = 0; j < 4; ++j) b[j] = Bs[kk][tx + 16 * j];
#pragma unroll
      for (int i = 0; i < 4; ++i)
#pragma unroll
        for (int j = 0; j < 4; ++j) acc[i][j] += a[i] * b[j];
    }
    __syncthreads();
  }
  const uint32_t fm = flagp ? flagp[0] : 1u;
#pragma unroll
  for (int i = 0; i < 4; ++i)
#pragma unroll
    for (int j = 0; j < 4; ++j) {
      const size_t off = (size_t)(m0 + ty + 16 * i) * N + n0 + tx + 16 * j;
      if (fm == 0) ((float*)C)[off] = acc[i][j];
      else         ((unsigned short*)C)[off] = f2bf(acc[i][j]);
    }
}

// In-place RoPE on q (B*T x NHEAD*128) and k (B*T x NKV*128).
// position = t = row % TSEQ; pair (i, i+64) within each head.
__global__ __launch_bounds__(256)
void rope_kernel(unsigned short* __restrict__ q, unsigned short* __restrict__ k) {
  const int QP = BATCH * TSEQ * NHEAD * 64;  // 4194304
  const int KP = BATCH * TSEQ * NKV * 64;    // 1048576
  int idx = blockIdx.x * 256 + threadIdx.x;
  unsigned short* p;
  int i, t;
  if (idx < QP) {
    i = idx & 63;
    int hh = (idx >> 6) & (NHEAD - 1);
    int row = idx >> 10;
    t = row & (TSEQ - 1);
    p = q + ((size_t)row << 11) + (hh << 7);
  } else {
    int j = idx - QP;
    if (j >= KP) return;
    i = j & 63;
    int hh = (j >> 6) & (NKV - 1);
    int row = j >> 8;
    t = row & (TSEQ - 1);
    p = k + ((size_t)row << 9) + (hh << 7);
  }
  float x1 = bf2f(p[i]), x2 = bf2f(p[i + 64]);
  // inv_freq = 10000^(-2i/128) = exp2(-(2i/128)*log2(10000))
  float freq = exp2f((float)i * (-2.0f / 128.0f) * 13.287712379549449f);
  float ang = (float)t * freq;
  float c = cosf(ang), s = sinf(ang);
  p[i]      = f2bf(x1 * c - x2 * s);
  p[i + 64] = f2bf(x2 * c + x1 * s);
}

// One 256-thread block per (b, h, qpos). All scores buffered in LDS.
// No infinities anywhere (fast-math safe): sentinel is -1e30f.
__global__ __launch_bounds__(256)
void attn_kernel(const unsigned short* __restrict__ q,
                 const unsigned short* __restrict__ k,
                 const unsigned short* __restrict__ v,
                 unsigned short* __restrict__ y,
                 const int* __restrict__ seq_lengths) {
  const int qpos = blockIdx.x & (TSEQ - 1);
  const int bh = blockIdx.x >> 11;
  const int h = bh & (NHEAD - 1);
  const int b = bh >> 4;
  const int tid = threadIdx.x;
  const int L = seq_lengths[b];
  unsigned short* yrow = y + ((size_t)(b * TSEQ + qpos) << 11) + (h << 7);
  if (qpos >= L) { if (tid < 128) yrow[tid] = 0; return; }
  const int kvoff = (h >> 2) << 7;
  const size_t bT = (size_t)b * TSEQ;

  __shared__ float qs[128];
  __shared__ float sc[MAXKEYS];
  __shared__ float redbuf[4];
  __shared__ float bm_s, bl_s;
  __shared__ float pacc[2][128];

  if (tid < 128) qs[tid] = bf2f(q[((bT + qpos) << 11) + (h << 7) + tid]) * 0.08838834764831843f;
  __syncthreads();

  int klo = qpos - WIN; if (klo < 0) klo = 0;
  const int nsink = klo < SINKN ? klo : SINKN;       // sink keys [0, nsink)
  const int total = nsink + (qpos - klo + 1);        // + window [klo, qpos]

  // Phase 1: scores into sc[] (sentinel -1e30f beyond total)
  for (int idx = tid; idx < MAXKEYS; idx += 256) {
    float s = -1e30f;
    if (idx < total) {
      const int key = idx < nsink ? idx : klo + (idx - nsink);
      const unsigned short* krow = k + ((bT + key) << 9) + kvoff;
      float dot = 0.f;
#pragma unroll
      for (int dd = 0; dd < 128; dd += 4) {
        ushort4 k4 = *(const ushort4*)(krow + dd);
        dot += qs[dd] * bf2f(k4.x) + qs[dd + 1] * bf2f(k4.y)
             + qs[dd + 2] * bf2f(k4.z) + qs[dd + 3] * bf2f(k4.w);
      }
      s = dot;  // qs pre-scaled by 1/sqrt(128)
    }
    sc[idx] = s;
  }
  __syncthreads();

  // Phase 2: block max
  float lm = -1e30f;
  for (int idx = tid; idx < MAXKEYS; idx += 256) lm = fmaxf(lm, sc[idx]);
#pragma unroll
  for (int off = 32; off; off >>= 1) lm = fmaxf(lm, __shfl_xor(lm, off, 64));
  if ((tid & 63) == 0) redbuf[tid >> 6] = lm;
  __syncthreads();
  if (tid == 0) bm_s = fmaxf(fmaxf(redbuf[0], redbuf[1]), fmaxf(redbuf[2], redbuf[3]));
  __syncthreads();
  const float m = bm_s;

  // Phase 3: exp + sum (sentinel -> exp(-huge) == 0, no NaN possible)
  float ls = 0.f;
  for (int idx = tid; idx < MAXKEYS; idx += 256) {
    float p = __expf(sc[idx] - m);
    sc[idx] = p;
    ls += p;
  }
#pragma unroll
  for (int off = 32; off; off >>= 1) ls += __shfl_xor(ls, off, 64);
  __syncthreads();  // sc[] rewrites + redbuf reuse ordering
  if ((tid & 63) == 0) redbuf[tid >> 6] = ls;
  __syncthreads();
  if (tid == 0) bl_s = redbuf[0] + redbuf[1] + redbuf[2] + redbuf[3];
  __syncthreads();
  const float inv_l = 1.0f / bl_s;  // bl_s >= 1 (exp(m-m)=1 term present)

  // Phase 4: PV. Two key-halves (interleaved) x 128 dims.
  float acc = 0.f;
  const int d = tid & 127;
  for (int j = tid >> 7; j < total; j += 2) {
    const int key = j < nsink ? j : klo + (j - nsink);
    acc += sc[j] * bf2f(v[((bT + key) << 9) + kvoff + d]);
  }
  pacc[tid >> 7][d] = acc;
  __syncthreads();
  if (tid < 128) yrow[tid] = f2bf((pacc[0][tid] + pacc[1][tid]) * inv_l);
}

extern "C" void kernel_launch(void* const* d_in, const int* in_sizes, int n_in,
                              void* d_out, int out_size, void* d_ws, size_t ws_size,
                              hipStream_t stream) {
  const int M = BATCH * TSEQ;                 // 4096
  const int NX  = M * CDIM;                   // 8,388,608
  const int NWQ = CDIM * CDIM;                // 4,194,304
  const int NWK = CDIM * KVDIM;               // 1,048,576
  const int NKVE = M * KVDIM;                 // 2,097,152

  uint32_t* flag = (uint32_t*)d_ws;
  unsigned short* base = (unsigned short*)((char*)d_ws + 16);
  unsigned short* qb  = base;                 // 8.4M
  unsigned short* kb  = qb + (size_t)NX;      // 2.1M
  unsigned short* vb  = kb + (size_t)NKVE;    // 2.1M
  unsigned short* yb  = vb + (size_t)NKVE;    // 8.4M
  unsigned short* xb  = yb + (size_t)NX;      // 8.4M
  unsigned short* wqb = xb + (size_t)NX;      // 4.2M
  unsigned short* wkb = wqb + (size_t)NWQ;    // 1.05M
  unsigned short* wvb = wkb + (size_t)NWK;    // 1.05M
  unsigned short* wob = wvb + (size_t)NWK;    // 4.2M

  const int* seq = (const int*)d_in[5];

  detect_kernel<<<1, 256, 0, stream>>>((const uint32_t*)d_in[0], flag);
  convert_kernel<<<(NX  + 255) / 256, 256, 0, stream>>>(d_in[0], xb,  NX,  flag);
  convert_kernel<<<(NWQ + 255) / 256, 256, 0, stream>>>(d_in[1], wqb, NWQ, flag);
  convert_kernel<<<(NWK + 255) / 256, 256, 0, stream>>>(d_in[2], wkb, NWK, flag);
  convert_kernel<<<(NWK + 255) / 256, 256, 0, stream>>>(d_in[3], wvb, NWK, flag);
  convert_kernel<<<(NWQ + 255) / 256, 256, 0, stream>>>(d_in[4], wob, NWQ, flag);

  gemm_bf16<<<dim3(CDIM / 64, M / 64), 256, 0, stream>>>(xb, wqb, qb, M, CDIM, CDIM, nullptr);
  gemm_bf16<<<dim3(KVDIM / 64, M / 64), 256, 0, stream>>>(xb, wkb, kb, M, KVDIM, CDIM, nullptr);
  gemm_bf16<<<dim3(KVDIM / 64, M / 64), 256, 0, stream>>>(xb, wvb, vb, M, KVDIM, CDIM, nullptr);
  const int rope_threads = BATCH * TSEQ * (NHEAD + NKV) * 64;    // 5,242,880
  rope_kernel<<<rope_threads / 256, 256, 0, stream>>>(qb, kb);
  attn_kernel<<<BATCH * NHEAD * TSEQ, 256, 0, stream>>>(qb, kb, vb, yb, seq);
  gemm_bf16<<<dim3(CDIM / 64, M / 64), 256, 0, stream>>>(yb, wob, d_out, M, CDIM, CDIM, flag);
}

// Round 4
// 1967.452 us; speedup vs baseline: 2.7353x; 2.7353x over previous
//
#include <hip/hip_runtime.h>
#include <stdint.h>

#define BATCH 2
#define TSEQ  2048
#define CDIM  2048
#define NHEAD 16
#define NKV   4
#define HDIM  128
#define KVDIM 512   /* NKV*HDIM */
#define WIN   1024
#define SINKN 4
#define QT    64

typedef unsigned short u16;
typedef __attribute__((ext_vector_type(8))) short bf16x8;
typedef __attribute__((ext_vector_type(4))) float f32x4;

__device__ __forceinline__ float bf2f(u16 u) {
  union { uint32_t i; float f; } w; w.i = ((uint32_t)u) << 16; return w.f;
}
__device__ __forceinline__ u16 f2bf(float f) {
  union { uint32_t i; float f; } w; w.f = f;
  return (u16)((w.i + 0x7fffu + ((w.i >> 16) & 1u)) >> 16);
}

// f32 (flag=0) vs packed bf16 (flag=1) input detector (see r2 notes).
__global__ __launch_bounds__(256)
void detect_kernel(const uint32_t* __restrict__ x, uint32_t* __restrict__ flag) {
  __shared__ int red[4];
  const int tid = threadIdx.x;
  int c = 0;
  for (int i = tid; i < 1024; i += 256) {
    uint32_t e = (x[i] >> 7) & 0xFFu;
    c += (e >= 100u && e <= 135u) ? 1 : 0;
  }
#pragma unroll
  for (int off = 32; off; off >>= 1) c += __shfl_xor(c, off, 64);
  if ((tid & 63) == 0) red[tid >> 6] = c;
  __syncthreads();
  if (tid == 0) flag[0] = ((red[0] + red[1] + red[2] + red[3]) > 512) ? 1u : 0u;
}

__global__ __launch_bounds__(256)
void convert_kernel(const void* __restrict__ src, u16* __restrict__ dst,
                    int n, const uint32_t* __restrict__ flag) {
  const int i = blockIdx.x * 256 + threadIdx.x;
  if (i >= n) return;
  if (flag[0]) dst[i] = ((const u16*)src)[i];
  else         dst[i] = f2bf(((const float*)src)[i]);
}

// C[M,N] = A[M,K] * B[K,N]; bf16 in, f32 acc. 64x64 tile, vector ALU.
__global__ __launch_bounds__(256)
void gemm_bf16(const u16* __restrict__ A, const u16* __restrict__ B,
               void* __restrict__ C, int M, int N, int K,
               const uint32_t* __restrict__ flagp) {
  __shared__ float As[16][65];
  __shared__ float Bs[16][65];
  const int tid = threadIdx.x;
  const int tx = tid & 15, ty = tid >> 4;
  const int m0 = blockIdx.y * 64, n0 = blockIdx.x * 64;
  float acc[4][4] = {};
  const int ar = tid >> 2, ac = (tid & 3) << 2;
  const int bk = tid >> 4, bc = (tid & 15) << 2;
  for (int k0 = 0; k0 < K; k0 += 16) {
    ushort4 a4 = *(const ushort4*)(A + (size_t)(m0 + ar) * K + k0 + ac);
    ushort4 b4 = *(const ushort4*)(B + (size_t)(k0 + bk) * N + n0 + bc);
    As[ac + 0][ar] = bf2f(a4.x);
    As[ac + 1][ar] = bf2f(a4.y);
    As[ac + 2][ar] = bf2f(a4.z);
    As[ac + 3][ar] = bf2f(a4.w);
    Bs[bk][bc + 0] = bf2f(b4.x);
    Bs[bk][bc + 1] = bf2f(b4.y);
    Bs[bk][bc + 2] = bf2f(b4.z);
    Bs[bk][bc + 3] = bf2f(b4.w);
    __syncthreads();
#pragma unroll
    for (int kk = 0; kk < 16; ++kk) {
      float a[4], b[4];
#pragma unroll
      for (int i = 0; i < 4; ++i) a[i] = As[kk][ty + 16 * i];
#pragma unroll
      for (int j = 0; j < 4; ++j) b[j] = Bs[kk][tx + 16 * j];
#pragma unroll
      for (int i = 0; i < 4; ++i)
#pragma unroll
        for (int j = 0; j < 4; ++j) acc[i][j] += a[i] * b[j];
    }
    __syncthreads();
  }
  const uint32_t fm = flagp ? flagp[0] : 1u;
#pragma unroll
  for (int i = 0; i < 4; ++i)
#pragma unroll
    for (int j = 0; j < 4; ++j) {
      const size_t off = (size_t)(m0 + ty + 16 * i) * N + n0 + tx + 16 * j;
      if (fm == 0) ((float*)C)[off] = acc[i][j];
      else         ((u16*)C)[off] = f2bf(acc[i][j]);
    }
}

__global__ __launch_bounds__(256)
void rope_kernel(u16* __restrict__ q, u16* __restrict__ k) {
  const int QP = BATCH * TSEQ * NHEAD * 64;
  const int KP = BATCH * TSEQ * NKV * 64;
  int idx = blockIdx.x * 256 + threadIdx.x;
  u16* p;
  int i, t;
  if (idx < QP) {
    i = idx & 63;
    int hh = (idx >> 6) & (NHEAD - 1);
    int row = idx >> 10;
    t = row & (TSEQ - 1);
    p = q + ((size_t)row << 11) + (hh << 7);
  } else {
    int j = idx - QP;
    if (j >= KP) return;
    i = j & 63;
    int hh = (j >> 6) & (NKV - 1);
    int row = j >> 8;
    t = row & (TSEQ - 1);
    p = k + ((size_t)row << 9) + (hh << 7);
  }
  float x1 = bf2f(p[i]), x2 = bf2f(p[i + 64]);
  float freq = exp2f((float)i * (-2.0f / 128.0f) * 13.287712379549449f);
  float ang = (float)t * freq;
  float c = cosf(ang), s = sinf(ang);
  p[i]      = f2bf(x1 * c - x2 * s);
  p[i + 64] = f2bf(x2 * c + x1 * s);
}

// MFMA flash attention. Block = 64-q tile for one (b,h); 4 waves x 16 rows.
// Layouts (gfx950 16x16x32 bf16, HW-verified mappings):
//   A-frag: A[m=lane&15][k=quad*8+j]   B-frag: B[k=quad*8+j][n=lane&15]
//   C/D:    col=lane&15, row=quad*4+reg
__global__ __launch_bounds__(256)
void attn_mfma(const u16* __restrict__ q, const u16* __restrict__ k,
               const u16* __restrict__ v, u16* __restrict__ y,
               const int* __restrict__ seq_lengths) {
  const int bid = blockIdx.x;
  const int q0 = (bid & 31) * QT;
  const int h  = (bid >> 5) & (NHEAD - 1);
  const int b  = bid >> 9;
  const int tid = threadIdx.x;
  const int w = tid >> 6;
  const int lane = tid & 63;
  const int quad = lane >> 4;
  const int lm = lane & 15;
  const int L = seq_lengths[b];
  const int kvoff = (h >> 2) << 7;
  const size_t bT = (size_t)b * TSEQ;

  // union: Qs[64][136] (17408B) lives only before the loop;
  // then Ks[32][136] (8704B) | Vt[128][40] (10240B) | Ps[4][16][40] (5120B)
  __shared__ u16 smem[12032];
  u16* Qs = smem;
  u16* Ks = smem;
  u16* Vt = smem + 4352;
  u16* Ps = smem + 9472;

  // stage Q tile (rows q0..q0+63, this head's 128 dims)
  {
    const int row = tid >> 2;
    const int cb = (tid & 3) * 32;
    const u16* src = q + ((bT + q0 + row) << 11) + (h << 7) + cb;
    u16* dst = Qs + row * 136 + cb;
#pragma unroll
    for (int s = 0; s < 4; ++s)
      *(uint4*)(dst + s * 8) = *(const uint4*)(src + s * 8);
  }
  __syncthreads();
  bf16x8 qf[4];
#pragma unroll
  for (int c = 0; c < 4; ++c)
    qf[c] = *(const bf16x8*)(Qs + (w * 16 + lm) * 136 + c * 32 + quad * 8);

  const int s0k = q0 - WIN > 0 ? q0 - WIN : 0;
  const int sink_extra = (s0k > 0) ? 1 : 0;   // sinks outside window range
  const int niter = ((q0 + QT - s0k) >> 5) + sink_extra;

  float mrow[4], lrow[4], alpha[4], p0[4], p1[4];
  f32x4 Oacc[8];
#pragma unroll
  for (int r = 0; r < 4; ++r) { mrow[r] = -1e30f; lrow[r] = 0.f; }
#pragma unroll
  for (int nt = 0; nt < 8; ++nt) Oacc[nt] = (f32x4){0.f, 0.f, 0.f, 0.f};

  const int qbase = q0 + w * 16;
  const float scale = 0.08838834764831843f;
  const int trow = tid >> 4;
  const int tc8 = (tid & 15) << 3;
  u16* Pw = Ps + w * 640;

  for (int it = 0; it < niter; ++it) {
    const bool is_sink = (sink_extra && it == 0);
    const int kbase = is_sink ? 0 : s0k + (it - sink_extra) * 32;
    __syncthreads();  // all waves done reading previous Ks/Vt (and Qs at it=0)
#pragma unroll
    for (int p = 0; p < 2; ++p) {
      const int krow = p * 16 + trow;
      uint4 kv4 = {0, 0, 0, 0}, vv4 = {0, 0, 0, 0};
      if (!is_sink || krow < SINKN) {
        const int key = kbase + krow;
        kv4 = *(const uint4*)(k + ((bT + key) << 9) + kvoff + tc8);
        vv4 = *(const uint4*)(v + ((bT + key) << 9) + kvoff + tc8);
      }
      *(uint4*)(Ks + krow * 136 + tc8) = kv4;
      const u16* vs = (const u16*)&vv4;
#pragma unroll
      for (int i = 0; i < 8; ++i) Vt[(tc8 + i) * 40 + krow] = vs[i];
    }
    __syncthreads();

    // S = Q K^T for two 16-key col tiles
    f32x4 sc0 = {0.f, 0.f, 0.f, 0.f}, sc1 = {0.f, 0.f, 0.f, 0.f};
#pragma unroll
    for (int c = 0; c < 4; ++c) {
      bf16x8 kf = *(const bf16x8*)(Ks + lm * 136 + c * 32 + quad * 8);
      sc0 = __builtin_amdgcn_mfma_f32_16x16x32_bf16(qf[c], kf, sc0, 0, 0, 0);
    }
#pragma unroll
    for (int c = 0; c < 4; ++c) {
      bf16x8 kf = *(const bf16x8*)(Ks + (16 + lm) * 136 + c * 32 + quad * 8);
      sc1 = __builtin_amdgcn_mfma_f32_16x16x32_bf16(qf[c], kf, sc1, 0, 0, 0);
    }

    const int key0 = (is_sink ? 0 : kbase) + lm;
    const int key1 = key0 + 16;
#pragma unroll
    for (int r = 0; r < 4; ++r) {
      const int qrow = qbase + quad * 4 + r;
      float v0 = sc0[r] * scale;
      float v1 = sc1[r] * scale;
      const bool ok0 = (key0 <= qrow) && ((qrow - key0 <= WIN) || (key0 < SINKN));
      const bool ok1 = (key1 <= qrow) && ((qrow - key1 <= WIN) || (key1 < SINKN));
      v0 = ok0 ? v0 : -1e30f;
      v1 = ok1 ? v1 : -1e30f;
      float tm = fmaxf(v0, v1);
#pragma unroll
      for (int off = 1; off < 16; off <<= 1) tm = fmaxf(tm, __shfl_xor(tm, off, 64));
      const float mn = fmaxf(mrow[r], tm);
      alpha[r] = __expf(mrow[r] - mn);
      mrow[r] = mn;
      p0[r] = __expf(v0 - mn);
      p1[r] = __expf(v1 - mn);
      float rs = p0[r] + p1[r];
#pragma unroll
      for (int off = 1; off < 16; off <<= 1) rs += __shfl_xor(rs, off, 64);
      lrow[r] = lrow[r] * alpha[r] + rs;
    }
    // P -> LDS (A-operand layout), rescale O
#pragma unroll
    for (int r = 0; r < 4; ++r) {
      const int row = quad * 4 + r;
      Pw[row * 40 + lm]      = f2bf(p0[r]);
      Pw[row * 40 + 16 + lm] = f2bf(p1[r]);
    }
#pragma unroll
    for (int nt = 0; nt < 8; ++nt)
#pragma unroll
      for (int r = 0; r < 4; ++r) Oacc[nt][r] *= alpha[r];
    // O += P V  (wave-local Ps: same-wave DS ordering, no barrier needed)
    bf16x8 pf = *(const bf16x8*)(Pw + lm * 40 + quad * 8);
#pragma unroll
    for (int nt = 0; nt < 8; ++nt) {
      bf16x8 vf = *(const bf16x8*)(Vt + (nt * 16 + lm) * 40 + quad * 8);
      Oacc[nt] = __builtin_amdgcn_mfma_f32_16x16x32_bf16(pf, vf, Oacc[nt], 0, 0, 0);
    }
  }

  float invl[4];
#pragma unroll
  for (int r = 0; r < 4; ++r) invl[r] = 1.0f / lrow[r];  // l>=exp(0)>0 always
#pragma unroll
  for (int nt = 0; nt < 8; ++nt)
#pragma unroll
    for (int r = 0; r < 4; ++r) {
      const int qrow = qbase + quad * 4 + r;
      const float val = (qrow < L) ? Oacc[nt][r] * invl[r] : 0.f;
      y[((bT + qrow) << 11) + (h << 7) + nt * 16 + lm] = f2bf(val);
    }
}

extern "C" void kernel_launch(void* const* d_in, const int* in_sizes, int n_in,
                              void* d_out, int out_size, void* d_ws, size_t ws_size,
                              hipStream_t stream) {
  const int M = BATCH * TSEQ;
  const int NX  = M * CDIM;
  const int NWQ = CDIM * CDIM;
  const int NWK = CDIM * KVDIM;
  const int NKVE = M * KVDIM;

  uint32_t* flag = (uint32_t*)d_ws;
  u16* base = (u16*)((char*)d_ws + 16);
  u16* qb  = base;
  u16* kb  = qb + (size_t)NX;
  u16* vb  = kb + (size_t)NKVE;
  u16* yb  = vb + (size_t)NKVE;
  u16* xb  = yb + (size_t)NX;
  u16* wqb = xb + (size_t)NX;
  u16* wkb = wqb + (size_t)NWQ;
  u16* wvb = wkb + (size_t)NWK;
  u16* wob = wvb + (size_t)NWK;

  const int* seq = (const int*)d_in[5];

  detect_kernel<<<1, 256, 0, stream>>>((const uint32_t*)d_in[0], flag);
  convert_kernel<<<(NX  + 255) / 256, 256, 0, stream>>>(d_in[0], xb,  NX,  flag);
  convert_kernel<<<(NWQ + 255) / 256, 256, 0, stream>>>(d_in[1], wqb, NWQ, flag);
  convert_kernel<<<(NWK + 255) / 256, 256, 0, stream>>>(d_in[2], wkb, NWK, flag);
  convert_kernel<<<(NWK + 255) / 256, 256, 0, stream>>>(d_in[3], wvb, NWK, flag);
  convert_kernel<<<(NWQ + 255) / 256, 256, 0, stream>>>(d_in[4], wob, NWQ, flag);

  gemm_bf16<<<dim3(CDIM / 64, M / 64), 256, 0, stream>>>(xb, wqb, qb, M, CDIM, CDIM, nullptr);
  gemm_bf16<<<dim3(KVDIM / 64, M / 64), 256, 0, stream>>>(xb, wkb, kb, M, KVDIM, CDIM, nullptr);
  gemm_bf16<<<dim3(KVDIM / 64, M / 64), 256, 0, stream>>>(xb, wvb, vb, M, KVDIM, CDIM, nullptr);
  const int rope_threads = BATCH * TSEQ * (NHEAD + NKV) * 64;
  rope_kernel<<<rope_threads / 256, 256, 0, stream>>>(qb, kb);
  attn_mfma<<<BATCH * NHEAD * (TSEQ / QT), 256, 0, stream>>>(qb, kb, vb, yb, seq);
  gemm_bf16<<<dim3(CDIM / 64, M / 64), 256, 0, stream>>>(yb, wob, d_out, M, CDIM, CDIM, flag);
}

// Round 5
// 591.619 us; speedup vs baseline: 9.0965x; 3.3255x over previous
//
#include <hip/hip_runtime.h>
#include <stdint.h>

#define BATCH 2
#define TSEQ  2048
#define CDIM  2048
#define NHEAD 16
#define NKV   4
#define HDIM  128
#define KVDIM 512
#define WIN   1024
#define SINKN 4
#define QT    64

typedef unsigned short u16;
typedef __attribute__((ext_vector_type(8))) short bf16x8;
typedef __attribute__((ext_vector_type(4))) float f32x4;
typedef __attribute__((address_space(3))) uint32_t as3_u32;
typedef const __attribute__((address_space(1))) uint32_t as1_u32;

__device__ __forceinline__ float bf2f(u16 u) {
  union { uint32_t i; float f; } w; w.i = ((uint32_t)u) << 16; return w.f;
}
__device__ __forceinline__ u16 f2bf(float f) {
  union { uint32_t i; float f; } w; w.f = f;
  return (u16)((w.i + 0x7fffu + ((w.i >> 16) & 1u)) >> 16);
}
__device__ __forceinline__ void gl2lds16(const u16* g, u16* l) {
  __builtin_amdgcn_global_load_lds((as1_u32*)g, (as3_u32*)l, 16, 0, 0);
}

// f32 (flag=0) vs packed bf16 (flag=1) input detector.
__global__ __launch_bounds__(256)
void detect_kernel(const uint32_t* __restrict__ x, uint32_t* __restrict__ flag) {
  __shared__ int red[4];
  const int tid = threadIdx.x;
  int c = 0;
  for (int i = tid; i < 1024; i += 256) {
    uint32_t e = (x[i] >> 7) & 0xFFu;
    c += (e >= 100u && e <= 135u) ? 1 : 0;
  }
#pragma unroll
  for (int off = 32; off; off >>= 1) c += __shfl_xor(c, off, 64);
  if ((tid & 63) == 0) red[tid >> 6] = c;
  __syncthreads();
  if (tid == 0) flag[0] = ((red[0] + red[1] + red[2] + red[3]) > 512) ? 1u : 0u;
}

__global__ __launch_bounds__(256)
void convert_kernel(const void* __restrict__ src, u16* __restrict__ dst,
                    int n, const uint32_t* __restrict__ flag) {
  const int i = blockIdx.x * 256 + threadIdx.x;
  if (i >= n) return;
  if (flag[0]) dst[i] = ((const u16*)src)[i];
  else         dst[i] = f2bf(((const float*)src)[i]);
}

// src [K][N] (f32 or bf16 per flag) -> dst [N][K] bf16. 32x32 LDS tiles.
__global__ __launch_bounds__(256)
void transpose_w(const void* __restrict__ src, u16* __restrict__ dst,
                 int K, int N, const uint32_t* __restrict__ flag) {
  __shared__ u16 t[32][33];
  const int n0 = blockIdx.x * 32, k0 = blockIdx.y * 32;
  const int tx = threadIdx.x & 31, ty = threadIdx.x >> 5;  // ty 0..7
  const uint32_t f = flag[0];
#pragma unroll
  for (int i = 0; i < 4; ++i) {
    const int kk = k0 + ty + i * 8;
    u16 val = f ? ((const u16*)src)[(size_t)kk * N + n0 + tx]
                : f2bf(((const float*)src)[(size_t)kk * N + n0 + tx]);
    t[ty + i * 8][tx] = val;
  }
  __syncthreads();
#pragma unroll
  for (int i = 0; i < 4; ++i)
    dst[(size_t)(n0 + ty + i * 8) * K + k0 + tx] = t[tx][ty + i * 8];
}

// C[M,N] = A[M,K] * BT[N,K]^T. MFMA 16x16x32 bf16, 128x128 tile, 4 waves 2x2,
// BK=32, global_load_lds width=16 staging (m97 structure).
__global__ __launch_bounds__(256)
void gemm_mfma_bt(const u16* __restrict__ A, const u16* __restrict__ BT,
                  void* __restrict__ C, int M, int N, int K,
                  const uint32_t* __restrict__ flagp) {
  __shared__ u16 Al[128 * 32];
  __shared__ u16 Bl[128 * 32];
  const int tid = threadIdx.x;
  const int w = tid >> 6, lane = tid & 63;
  const int quad = lane >> 4, lm = lane & 15;
  const int wm = w >> 1, wn = w & 1;
  const int m0 = blockIdx.y * 128, n0 = blockIdx.x * 128;

  f32x4 acc[4][4];
#pragma unroll
  for (int i = 0; i < 4; ++i)
#pragma unroll
    for (int j = 0; j < 4; ++j) acc[i][j] = (f32x4){0.f, 0.f, 0.f, 0.f};

  // staging: wave w covers rows [w*32, w*32+32) of each 128x32 tile;
  // lane r=lane>>2 (16 rows/instr), c=(lane&3)*8 elems; LDS = base+lane*16B.
  const int sr = lane >> 2;
  const int sc = (lane & 3) << 3;
  const u16* Ag = A  + (size_t)(m0 + w * 32 + sr) * K + sc;
  const u16* Bg = BT + (size_t)(n0 + w * 32 + sr) * K + sc;
  u16* Alw = Al + (w * 32) * 32;
  u16* Blw = Bl + (w * 32) * 32;

  for (int k0 = 0; k0 < K; k0 += 32) {
    __syncthreads();  // prior-iter LDS reads complete before overwrite
    gl2lds16(Ag + k0,                    Alw);
    gl2lds16(Ag + (size_t)16 * K + k0,   Alw + 16 * 32);
    gl2lds16(Bg + k0,                    Blw);
    gl2lds16(Bg + (size_t)16 * K + k0,   Blw + 16 * 32);
    __syncthreads();  // drains vmcnt: staged data visible

    bf16x8 af[4], bfr[4];
#pragma unroll
    for (int mi = 0; mi < 4; ++mi)
      af[mi] = *(const bf16x8*)(Al + (wm * 64 + mi * 16 + lm) * 32 + quad * 8);
#pragma unroll
    for (int ni = 0; ni < 4; ++ni)
      bfr[ni] = *(const bf16x8*)(Bl + (wn * 64 + ni * 16 + lm) * 32 + quad * 8);
#pragma unroll
    for (int mi = 0; mi < 4; ++mi)
#pragma unroll
      for (int ni = 0; ni < 4; ++ni)
        acc[mi][ni] = __builtin_amdgcn_mfma_f32_16x16x32_bf16(af[mi], bfr[ni], acc[mi][ni], 0, 0, 0);
  }

  const uint32_t fm = flagp ? flagp[0] : 1u;
#pragma unroll
  for (int mi = 0; mi < 4; ++mi)
#pragma unroll
    for (int ni = 0; ni < 4; ++ni)
#pragma unroll
      for (int r = 0; r < 4; ++r) {
        const int row = m0 + wm * 64 + mi * 16 + quad * 4 + r;
        const int col = n0 + wn * 64 + ni * 16 + lm;
        const float val = acc[mi][ni][r];
        if (fm == 0) ((float*)C)[(size_t)row * N + col] = val;
        else         ((u16*)C)[(size_t)row * N + col] = f2bf(val);
      }
}

// RoPE in-place on q [B*T][2048] and fused kv [B*T][1024] (k = cols 0..511).
__global__ __launch_bounds__(256)
void rope_kernel(u16* __restrict__ q, u16* __restrict__ kv) {
  const int QP = BATCH * TSEQ * NHEAD * 64;
  const int KP = BATCH * TSEQ * NKV * 64;
  int idx = blockIdx.x * 256 + threadIdx.x;
  u16* p;
  int i, t;
  if (idx < QP) {
    i = idx & 63;
    int hh = (idx >> 6) & (NHEAD - 1);
    int row = idx >> 10;
    t = row & (TSEQ - 1);
    p = q + ((size_t)row << 11) + (hh << 7);
  } else {
    int j = idx - QP;
    if (j >= KP) return;
    i = j & 63;
    int hh = (j >> 6) & (NKV - 1);
    int row = j >> 8;
    t = row & (TSEQ - 1);
    p = kv + ((size_t)row << 10) + (hh << 7);
  }
  float x1 = bf2f(p[i]), x2 = bf2f(p[i + 64]);
  float freq = exp2f((float)i * (-2.0f / 128.0f) * 13.287712379549449f);
  float ang = (float)t * freq;
  float c = cosf(ang), s = sinf(ang);
  p[i]      = f2bf(x1 * c - x2 * s);
  p[i + 64] = f2bf(x2 * c + x1 * s);
}

// MFMA flash attention (r4, ref-passed), kv fused buffer [token][1024].
__global__ __launch_bounds__(256)
void attn_mfma(const u16* __restrict__ q, const u16* __restrict__ kv,
               u16* __restrict__ y, const int* __restrict__ seq_lengths) {
  const int bid = blockIdx.x;
  const int q0 = (bid & 31) * QT;
  const int h  = (bid >> 5) & (NHEAD - 1);
  const int b  = bid >> 9;
  const int tid = threadIdx.x;
  const int w = tid >> 6;
  const int lane = tid & 63;
  const int quad = lane >> 4;
  const int lm = lane & 15;
  const int L = seq_lengths[b];
  const int kvoff = (h >> 2) << 7;
  const size_t bT = (size_t)b * TSEQ;

  __shared__ u16 smem[12032];
  u16* Qs = smem;
  u16* Ks = smem;
  u16* Vt = smem + 4352;
  u16* Ps = smem + 9472;

  {
    const int row = tid >> 2;
    const int cb = (tid & 3) * 32;
    const u16* src = q + ((bT + q0 + row) << 11) + (h << 7) + cb;
    u16* dst = Qs + row * 136 + cb;
#pragma unroll
    for (int s = 0; s < 4; ++s)
      *(uint4*)(dst + s * 8) = *(const uint4*)(src + s * 8);
  }
  __syncthreads();
  bf16x8 qf[4];
#pragma unroll
  for (int c = 0; c < 4; ++c)
    qf[c] = *(const bf16x8*)(Qs + (w * 16 + lm) * 136 + c * 32 + quad * 8);

  const int s0k = q0 - WIN > 0 ? q0 - WIN : 0;
  const int sink_extra = (s0k > 0) ? 1 : 0;
  const int niter = ((q0 + QT - s0k) >> 5) + sink_extra;

  float mrow[4], lrow[4], alpha[4], p0[4], p1[4];
  f32x4 Oacc[8];
#pragma unroll
  for (int r = 0; r < 4; ++r) { mrow[r] = -1e30f; lrow[r] = 0.f; }
#pragma unroll
  for (int nt = 0; nt < 8; ++nt) Oacc[nt] = (f32x4){0.f, 0.f, 0.f, 0.f};

  const int qbase = q0 + w * 16;
  const float scale = 0.08838834764831843f;
  const int trow = tid >> 4;
  const int tc8 = (tid & 15) << 3;
  u16* Pw = Ps + w * 640;

  for (int it = 0; it < niter; ++it) {
    const bool is_sink = (sink_extra && it == 0);
    const int kbase = is_sink ? 0 : s0k + (it - sink_extra) * 32;
    __syncthreads();
#pragma unroll
    for (int p = 0; p < 2; ++p) {
      const int krow = p * 16 + trow;
      uint4 kv4 = {0, 0, 0, 0}, vv4 = {0, 0, 0, 0};
      if (!is_sink || krow < SINKN) {
        const int key = kbase + krow;
        const u16* base = kv + ((bT + key) << 10) + kvoff + tc8;
        kv4 = *(const uint4*)(base);
        vv4 = *(const uint4*)(base + 512);
      }
      *(uint4*)(Ks + krow * 136 + tc8) = kv4;
      const u16* vs = (const u16*)&vv4;
#pragma unroll
      for (int i = 0; i < 8; ++i) Vt[(tc8 + i) * 40 + krow] = vs[i];
    }
    __syncthreads();

    f32x4 sc0 = {0.f, 0.f, 0.f, 0.f}, sc1 = {0.f, 0.f, 0.f, 0.f};
#pragma unroll
    for (int c = 0; c < 4; ++c) {
      bf16x8 kf = *(const bf16x8*)(Ks + lm * 136 + c * 32 + quad * 8);
      sc0 = __builtin_amdgcn_mfma_f32_16x16x32_bf16(qf[c], kf, sc0, 0, 0, 0);
    }
#pragma unroll
    for (int c = 0; c < 4; ++c) {
      bf16x8 kf = *(const bf16x8*)(Ks + (16 + lm) * 136 + c * 32 + quad * 8);
      sc1 = __builtin_amdgcn_mfma_f32_16x16x32_bf16(qf[c], kf, sc1, 0, 0, 0);
    }

    const int key0 = (is_sink ? 0 : kbase) + lm;
    const int key1 = key0 + 16;
#pragma unroll
    for (int r = 0; r < 4; ++r) {
      const int qrow = qbase + quad * 4 + r;
      float v0 = sc0[r] * scale;
      float v1 = sc1[r] * scale;
      const bool ok0 = (key0 <= qrow) && ((qrow - key0 <= WIN) || (key0 < SINKN));
      const bool ok1 = (key1 <= qrow) && ((qrow - key1 <= WIN) || (key1 < SINKN));
      v0 = ok0 ? v0 : -1e30f;
      v1 = ok1 ? v1 : -1e30f;
      float tm = fmaxf(v0, v1);
#pragma unroll
      for (int off = 1; off < 16; off <<= 1) tm = fmaxf(tm, __shfl_xor(tm, off, 64));
      const float mn = fmaxf(mrow[r], tm);
      alpha[r] = __expf(mrow[r] - mn);
      mrow[r] = mn;
      p0[r] = __expf(v0 - mn);
      p1[r] = __expf(v1 - mn);
      float rs = p0[r] + p1[r];
#pragma unroll
      for (int off = 1; off < 16; off <<= 1) rs += __shfl_xor(rs, off, 64);
      lrow[r] = lrow[r] * alpha[r] + rs;
    }
#pragma unroll
    for (int r = 0; r < 4; ++r) {
      const int row = quad * 4 + r;
      Pw[row * 40 + lm]      = f2bf(p0[r]);
      Pw[row * 40 + 16 + lm] = f2bf(p1[r]);
    }
#pragma unroll
    for (int nt = 0; nt < 8; ++nt)
#pragma unroll
      for (int r = 0; r < 4; ++r) Oacc[nt][r] *= alpha[r];
    bf16x8 pf = *(const bf16x8*)(Pw + lm * 40 + quad * 8);
#pragma unroll
    for (int nt = 0; nt < 8; ++nt) {
      bf16x8 vf = *(const bf16x8*)(Vt + (nt * 16 + lm) * 40 + quad * 8);
      Oacc[nt] = __builtin_amdgcn_mfma_f32_16x16x32_bf16(pf, vf, Oacc[nt], 0, 0, 0);
    }
  }

  float invl[4];
#pragma unroll
  for (int r = 0; r < 4; ++r) invl[r] = 1.0f / lrow[r];
#pragma unroll
  for (int nt = 0; nt < 8; ++nt)
#pragma unroll
    for (int r = 0; r < 4; ++r) {
      const int qrow = qbase + quad * 4 + r;
      const float val = (qrow < L) ? Oacc[nt][r] * invl[r] : 0.f;
      y[((bT + qrow) << 11) + (h << 7) + nt * 16 + lm] = f2bf(val);
    }
}

extern "C" void kernel_launch(void* const* d_in, const int* in_sizes, int n_in,
                              void* d_out, int out_size, void* d_ws, size_t ws_size,
                              hipStream_t stream) {
  const int M = BATCH * TSEQ;                 // 4096
  const int NX  = M * CDIM;                   // 8,388,608

  uint32_t* flag = (uint32_t*)d_ws;
  u16* base = (u16*)((char*)d_ws + 16);
  u16* qb   = base;                               // [4096][2048]
  u16* kvb  = qb  + (size_t)NX;                   // [4096][1024] fused k|v
  u16* yb   = kvb + (size_t)M * 1024;             // [4096][2048]
  u16* xb   = yb  + (size_t)NX;                   // [4096][2048]
  u16* wqT  = xb  + (size_t)NX;                   // [2048][2048]
  u16* wkvT = wqT + (size_t)CDIM * CDIM;          // [1024][2048] (WkT | WvT)
  u16* woT  = wkvT + (size_t)1024 * CDIM;         // [2048][2048]

  const int* seq = (const int*)d_in[5];

  detect_kernel<<<1, 256, 0, stream>>>((const uint32_t*)d_in[0], flag);
  convert_kernel<<<(NX + 255) / 256, 256, 0, stream>>>(d_in[0], xb, NX, flag);
  // weights -> bf16, transposed to [N][K]
  transpose_w<<<dim3(CDIM / 32, CDIM / 32), 256, 0, stream>>>(d_in[1], wqT, CDIM, CDIM, flag);
  transpose_w<<<dim3(KVDIM / 32, CDIM / 32), 256, 0, stream>>>(d_in[2], wkvT, CDIM, KVDIM, flag);
  transpose_w<<<dim3(KVDIM / 32, CDIM / 32), 256, 0, stream>>>(d_in[3], wkvT + (size_t)KVDIM * CDIM, CDIM, KVDIM, flag);
  transpose_w<<<dim3(CDIM / 32, CDIM / 32), 256, 0, stream>>>(d_in[4], woT, CDIM, CDIM, flag);

  gemm_mfma_bt<<<dim3(CDIM / 128, M / 128), 256, 0, stream>>>(xb, wqT, qb, M, CDIM, CDIM, nullptr);
  gemm_mfma_bt<<<dim3(1024 / 128, M / 128), 256, 0, stream>>>(xb, wkvT, kvb, M, 1024, CDIM, nullptr);
  const int rope_threads = BATCH * TSEQ * (NHEAD + NKV) * 64;
  rope_kernel<<<rope_threads / 256, 256, 0, stream>>>(qb, kvb);
  attn_mfma<<<BATCH * NHEAD * (TSEQ / QT), 256, 0, stream>>>(qb, kvb, yb, seq);
  gemm_mfma_bt<<<dim3(CDIM / 128, M / 128), 256, 0, stream>>>(yb, woT, d_out, M, CDIM, CDIM, flag);
}

// Round 6
// 505.016 us; speedup vs baseline: 10.6564x; 1.1715x over previous
//
#include <hip/hip_runtime.h>
#include <stdint.h>

#define BATCH 2
#define TSEQ  2048
#define CDIM  2048
#define NHEAD 16
#define NKV   4
#define HDIM  128
#define KVDIM 512
#define WIN   1024
#define SINKN 4
#define QT    64

typedef unsigned short u16;
typedef __attribute__((ext_vector_type(8))) short bf16x8;
typedef __attribute__((ext_vector_type(4))) float f32x4;
typedef __attribute__((address_space(3))) uint32_t as3_u32;
typedef const __attribute__((address_space(1))) uint32_t as1_u32;

__device__ __forceinline__ float bf2f(u16 u) {
  union { uint32_t i; float f; } w; w.i = ((uint32_t)u) << 16; return w.f;
}
__device__ __forceinline__ u16 f2bf(float f) {
  union { uint32_t i; float f; } w; w.f = f;
  return (u16)((w.i + 0x7fffu + ((w.i >> 16) & 1u)) >> 16);
}
__device__ __forceinline__ void gl2lds16(const u16* g, u16* l) {
  __builtin_amdgcn_global_load_lds((as1_u32*)g, (as3_u32*)l, 16, 0, 0);
}

// f32 (flag=0) vs packed bf16 (flag=1) input detector.
__global__ __launch_bounds__(256)
void detect_kernel(const uint32_t* __restrict__ x, uint32_t* __restrict__ flag) {
  __shared__ int red[4];
  const int tid = threadIdx.x;
  int c = 0;
  for (int i = tid; i < 1024; i += 256) {
    uint32_t e = (x[i] >> 7) & 0xFFu;
    c += (e >= 100u && e <= 135u) ? 1 : 0;
  }
#pragma unroll
  for (int off = 32; off; off >>= 1) c += __shfl_xor(c, off, 64);
  if ((tid & 63) == 0) red[tid >> 6] = c;
  __syncthreads();
  if (tid == 0) flag[0] = ((red[0] + red[1] + red[2] + red[3]) > 512) ? 1u : 0u;
}

__global__ __launch_bounds__(256)
void convert_kernel(const void* __restrict__ src, u16* __restrict__ dst,
                    int n, const uint32_t* __restrict__ flag) {
  const int i = blockIdx.x * 256 + threadIdx.x;
  if (i >= n) return;
  if (flag[0]) dst[i] = ((const u16*)src)[i];
  else         dst[i] = f2bf(((const float*)src)[i]);
}

// src [K][N] (f32 or bf16 per flag) -> dst [N][K] bf16. 32x32 LDS tiles.
__global__ __launch_bounds__(256)
void transpose_w(const void* __restrict__ src, u16* __restrict__ dst,
                 int K, int N, const uint32_t* __restrict__ flag) {
  __shared__ u16 t[32][33];
  const int n0 = blockIdx.x * 32, k0 = blockIdx.y * 32;
  const int tx = threadIdx.x & 31, ty = threadIdx.x >> 5;
  const uint32_t f = flag[0];
#pragma unroll
  for (int i = 0; i < 4; ++i) {
    const int kk = k0 + ty + i * 8;
    u16 val = f ? ((const u16*)src)[(size_t)kk * N + n0 + tx]
                : f2bf(((const float*)src)[(size_t)kk * N + n0 + tx]);
    t[ty + i * 8][tx] = val;
  }
  __syncthreads();
#pragma unroll
  for (int i = 0; i < 4; ++i)
    dst[(size_t)(n0 + ty + i * 8) * K + k0 + tx] = t[tx][ty + i * 8];
}

// C[M,N] = A[M,K] * BT[N,K]^T. MFMA 16x16x32 bf16, 128x128 tile (m97 recipe).
__global__ __launch_bounds__(256)
void gemm_mfma_bt(const u16* __restrict__ A, const u16* __restrict__ BT,
                  void* __restrict__ C, int M, int N, int K,
                  const uint32_t* __restrict__ flagp) {
  __shared__ u16 Al[128 * 32];
  __shared__ u16 Bl[128 * 32];
  const int tid = threadIdx.x;
  const int w = tid >> 6, lane = tid & 63;
  const int quad = lane >> 4, lm = lane & 15;
  const int wm = w >> 1, wn = w & 1;
  const int m0 = blockIdx.y * 128, n0 = blockIdx.x * 128;

  f32x4 acc[4][4];
#pragma unroll
  for (int i = 0; i < 4; ++i)
#pragma unroll
    for (int j = 0; j < 4; ++j) acc[i][j] = (f32x4){0.f, 0.f, 0.f, 0.f};

  const int sr = lane >> 2;
  const int sc = (lane & 3) << 3;
  const u16* Ag = A  + (size_t)(m0 + w * 32 + sr) * K + sc;
  const u16* Bg = BT + (size_t)(n0 + w * 32 + sr) * K + sc;
  u16* Alw = Al + (w * 32) * 32;
  u16* Blw = Bl + (w * 32) * 32;

  for (int k0 = 0; k0 < K; k0 += 32) {
    __syncthreads();
    gl2lds16(Ag + k0,                  Alw);
    gl2lds16(Ag + (size_t)16 * K + k0, Alw + 16 * 32);
    gl2lds16(Bg + k0,                  Blw);
    gl2lds16(Bg + (size_t)16 * K + k0, Blw + 16 * 32);
    __syncthreads();

    bf16x8 af[4], bfr[4];
#pragma unroll
    for (int mi = 0; mi < 4; ++mi)
      af[mi] = *(const bf16x8*)(Al + (wm * 64 + mi * 16 + lm) * 32 + quad * 8);
#pragma unroll
    for (int ni = 0; ni < 4; ++ni)
      bfr[ni] = *(const bf16x8*)(Bl + (wn * 64 + ni * 16 + lm) * 32 + quad * 8);
#pragma unroll
    for (int mi = 0; mi < 4; ++mi)
#pragma unroll
      for (int ni = 0; ni < 4; ++ni)
        acc[mi][ni] = __builtin_amdgcn_mfma_f32_16x16x32_bf16(af[mi], bfr[ni], acc[mi][ni], 0, 0, 0);
  }

  const uint32_t fm = flagp ? flagp[0] : 1u;
#pragma unroll
  for (int mi = 0; mi < 4; ++mi)
#pragma unroll
    for (int ni = 0; ni < 4; ++ni)
#pragma unroll
      for (int r = 0; r < 4; ++r) {
        const int row = m0 + wm * 64 + mi * 16 + quad * 4 + r;
        const int col = n0 + wn * 64 + ni * 16 + lm;
        const float val = acc[mi][ni][r];
        if (fm == 0) ((float*)C)[(size_t)row * N + col] = val;
        else         ((u16*)C)[(size_t)row * N + col] = f2bf(val);
      }
}

// RoPE in-place on q [B*T][2048] and fused kv [B*T][1024] (k = cols 0..511).
__global__ __launch_bounds__(256)
void rope_kernel(u16* __restrict__ q, u16* __restrict__ kv) {
  const int QP = BATCH * TSEQ * NHEAD * 64;
  const int KP = BATCH * TSEQ * NKV * 64;
  int idx = blockIdx.x * 256 + threadIdx.x;
  u16* p;
  int i, t;
  if (idx < QP) {
    i = idx & 63;
    int hh = (idx >> 6) & (NHEAD - 1);
    int row = idx >> 10;
    t = row & (TSEQ - 1);
    p = q + ((size_t)row << 11) + (hh << 7);
  } else {
    int j = idx - QP;
    if (j >= KP) return;
    i = j & 63;
    int hh = (j >> 6) & (NKV - 1);
    int row = j >> 8;
    t = row & (TSEQ - 1);
    p = kv + ((size_t)row << 10) + (hh << 7);
  }
  float x1 = bf2f(p[i]), x2 = bf2f(p[i + 64]);
  float freq = exp2f((float)i * (-2.0f / 128.0f) * 13.287712379549449f);
  float ang = (float)t * freq;
  float c = cosf(ang), s = sinf(ang);
  p[i]      = f2bf(x1 * c - x2 * s);
  p[i + 64] = f2bf(x2 * c + x1 * s);
}

// MFMA flash attention. r6: Vt XOR-swizzle (bank conflicts), K/V reg
// double-buffer (latency overlap), LPT q-tile order (tail fill).
__global__ __launch_bounds__(256)
void attn_mfma(const u16* __restrict__ q, const u16* __restrict__ kv,
               u16* __restrict__ y, const int* __restrict__ seq_lengths) {
  const int bid = blockIdx.x;
  const int q0 = (31 - (bid & 31)) * QT;   // LPT: longest tiles first
  const int h  = (bid >> 5) & (NHEAD - 1);
  const int b  = bid >> 9;
  const int tid = threadIdx.x;
  const int w = tid >> 6;
  const int lane = tid & 63;
  const int quad = lane >> 4;
  const int lm = lane & 15;
  const int L = seq_lengths[b];
  const int kvoff = (h >> 2) << 7;
  const size_t bT = (size_t)b * TSEQ;

  __shared__ u16 smem[12032];
  u16* Qs = smem;
  u16* Ks = smem;
  u16* Vt = smem + 4352;
  u16* Ps = smem + 9472;

  {
    const int row = tid >> 2;
    const int cb = (tid & 3) * 32;
    const u16* src = q + ((bT + q0 + row) << 11) + (h << 7) + cb;
    u16* dst = Qs + row * 136 + cb;
#pragma unroll
    for (int s = 0; s < 4; ++s)
      *(uint4*)(dst + s * 8) = *(const uint4*)(src + s * 8);
  }
  __syncthreads();
  bf16x8 qf[4];
#pragma unroll
  for (int c = 0; c < 4; ++c)
    qf[c] = *(const bf16x8*)(Qs + (w * 16 + lm) * 136 + c * 32 + quad * 8);

  const int s0k = q0 - WIN > 0 ? q0 - WIN : 0;
  const int sink_extra = (s0k > 0) ? 1 : 0;
  const int niter = ((q0 + QT - s0k) >> 5) + sink_extra;

  float mrow[4], lrow[4], alpha[4], p0[4], p1[4];
  f32x4 Oacc[8];
#pragma unroll
  for (int r = 0; r < 4; ++r) { mrow[r] = -1e30f; lrow[r] = 0.f; }
#pragma unroll
  for (int nt = 0; nt < 8; ++nt) Oacc[nt] = (f32x4){0.f, 0.f, 0.f, 0.f};

  const int qbase = q0 + w * 16;
  const float scale = 0.08838834764831843f;
  const int trow = tid >> 4;
  const int tc8 = (tid & 15) << 3;
  u16* Pw = Ps + w * 640;

  // register double-buffer of K/V global loads
  uint4 kr[2], vr[2];
  auto load_chunk = [&](int it) {
    const bool is_s = (sink_extra && it == 0);
    const int kb = is_s ? 0 : s0k + (it - sink_extra) * 32;
#pragma unroll
    for (int p = 0; p < 2; ++p) {
      const int krow = p * 16 + trow;
      uint4 kz = {0, 0, 0, 0}, vz = {0, 0, 0, 0};
      if (!is_s || krow < SINKN) {
        const u16* base = kv + ((bT + kb + krow) << 10) + kvoff + tc8;
        kz = *(const uint4*)(base);
        vz = *(const uint4*)(base + 512);
      }
      kr[p] = kz; vr[p] = vz;
    }
  };
  load_chunk(0);

  // Vt swizzle: entry (dim,key) stored at dim*40 + ((kg^((dim>>3)&3))<<3)|kl
  const int swz_hi = (tc8 >> 3) & 3;  // (dim>>3)&3, const across i

  for (int it = 0; it < niter; ++it) {
    const bool is_sink = (sink_extra && it == 0);
    const int kbase = is_sink ? 0 : s0k + (it - sink_extra) * 32;
    __syncthreads();  // all waves done reading previous Ks/Vt (and Qs at it=0)
#pragma unroll
    for (int p = 0; p < 2; ++p) {
      const int krow = p * 16 + trow;
      *(uint4*)(Ks + krow * 136 + tc8) = kr[p];
      const u16* vs = (const u16*)&vr[p];
      const int skey = ((((krow >> 3) ^ swz_hi) << 3) | (krow & 7));
#pragma unroll
      for (int i = 0; i < 8; ++i) Vt[(tc8 + i) * 40 + skey] = vs[i];
    }
    if (it + 1 < niter) load_chunk(it + 1);  // overlap with compute below
    __syncthreads();

    f32x4 sc0 = {0.f, 0.f, 0.f, 0.f}, sc1 = {0.f, 0.f, 0.f, 0.f};
#pragma unroll
    for (int c = 0; c < 4; ++c) {
      bf16x8 kf = *(const bf16x8*)(Ks + lm * 136 + c * 32 + quad * 8);
      sc0 = __builtin_amdgcn_mfma_f32_16x16x32_bf16(qf[c], kf, sc0, 0, 0, 0);
    }
#pragma unroll
    for (int c = 0; c < 4; ++c) {
      bf16x8 kf = *(const bf16x8*)(Ks + (16 + lm) * 136 + c * 32 + quad * 8);
      sc1 = __builtin_amdgcn_mfma_f32_16x16x32_bf16(qf[c], kf, sc1, 0, 0, 0);
    }

    const int key0 = (is_sink ? 0 : kbase) + lm;
    const int key1 = key0 + 16;
#pragma unroll
    for (int r = 0; r < 4; ++r) {
      const int qrow = qbase + quad * 4 + r;
      float v0 = sc0[r] * scale;
      float v1 = sc1[r] * scale;
      const bool ok0 = (key0 <= qrow) && ((qrow - key0 <= WIN) || (key0 < SINKN));
      const bool ok1 = (key1 <= qrow) && ((qrow - key1 <= WIN) || (key1 < SINKN));
      v0 = ok0 ? v0 : -1e30f;
      v1 = ok1 ? v1 : -1e30f;
      float tm = fmaxf(v0, v1);
#pragma unroll
      for (int off = 1; off < 16; off <<= 1) tm = fmaxf(tm, __shfl_xor(tm, off, 64));
      const float mn = fmaxf(mrow[r], tm);
      alpha[r] = __expf(mrow[r] - mn);
      mrow[r] = mn;
      p0[r] = __expf(v0 - mn);
      p1[r] = __expf(v1 - mn);
      float rs = p0[r] + p1[r];
#pragma unroll
      for (int off = 1; off < 16; off <<= 1) rs += __shfl_xor(rs, off, 64);
      lrow[r] = lrow[r] * alpha[r] + rs;
    }
#pragma unroll
    for (int r = 0; r < 4; ++r) {
      const int row = quad * 4 + r;
      Pw[row * 40 + lm]      = f2bf(p0[r]);
      Pw[row * 40 + 16 + lm] = f2bf(p1[r]);
    }
#pragma unroll
    for (int nt = 0; nt < 8; ++nt)
#pragma unroll
      for (int r = 0; r < 4; ++r) Oacc[nt][r] *= alpha[r];
    bf16x8 pf = *(const bf16x8*)(Pw + lm * 40 + quad * 8);
#pragma unroll
    for (int nt = 0; nt < 8; ++nt) {
      const int sg = (quad ^ ((nt * 2 + (lm >> 3)) & 3)) << 3;
      bf16x8 vf = *(const bf16x8*)(Vt + (nt * 16 + lm) * 40 + sg);
      Oacc[nt] = __builtin_amdgcn_mfma_f32_16x16x32_bf16(pf, vf, Oacc[nt], 0, 0, 0);
    }
  }

  float invl[4];
#pragma unroll
  for (int r = 0; r < 4; ++r) invl[r] = 1.0f / lrow[r];
#pragma unroll
  for (int nt = 0; nt < 8; ++nt)
#pragma unroll
    for (int r = 0; r < 4; ++r) {
      const int qrow = qbase + quad * 4 + r;
      const float val = (qrow < L) ? Oacc[nt][r] * invl[r] : 0.f;
      y[((bT + qrow) << 11) + (h << 7) + nt * 16 + lm] = f2bf(val);
    }
}

extern "C" void kernel_launch(void* const* d_in, const int* in_sizes, int n_in,
                              void* d_out, int out_size, void* d_ws, size_t ws_size,
                              hipStream_t stream) {
  const int M = BATCH * TSEQ;                 // 4096
  const int NX  = M * CDIM;                   // 8,388,608

  uint32_t* flag = (uint32_t*)d_ws;
  u16* base = (u16*)((char*)d_ws + 16);
  u16* qb   = base;                               // [4096][2048]
  u16* kvb  = qb  + (size_t)NX;                   // [4096][1024] fused k|v
  u16* yb   = kvb + (size_t)M * 1024;             // [4096][2048]
  u16* xb   = yb  + (size_t)NX;                   // [4096][2048]
  u16* wqT  = xb  + (size_t)NX;                   // [2048][2048]
  u16* wkvT = wqT + (size_t)CDIM * CDIM;          // [1024][2048] (WkT | WvT)
  u16* woT  = wkvT + (size_t)1024 * CDIM;         // [2048][2048]

  const int* seq = (const int*)d_in[5];

  detect_kernel<<<1, 256, 0, stream>>>((const uint32_t*)d_in[0], flag);
  convert_kernel<<<(NX + 255) / 256, 256, 0, stream>>>(d_in[0], xb, NX, flag);
  transpose_w<<<dim3(CDIM / 32, CDIM / 32), 256, 0, stream>>>(d_in[1], wqT, CDIM, CDIM, flag);
  transpose_w<<<dim3(KVDIM / 32, CDIM / 32), 256, 0, stream>>>(d_in[2], wkvT, CDIM, KVDIM, flag);
  transpose_w<<<dim3(KVDIM / 32, CDIM / 32), 256, 0, stream>>>(d_in[3], wkvT + (size_t)KVDIM * CDIM, CDIM, KVDIM, flag);
  transpose_w<<<dim3(CDIM / 32, CDIM / 32), 256, 0, stream>>>(d_in[4], woT, CDIM, CDIM, flag);

  gemm_mfma_bt<<<dim3(CDIM / 128, M / 128), 256, 0, stream>>>(xb, wqT, qb, M, CDIM, CDIM, nullptr);
  gemm_mfma_bt<<<dim3(1024 / 128, M / 128), 256, 0, stream>>>(xb, wkvT, kvb, M, 1024, CDIM, nullptr);
  const int rope_threads = BATCH * TSEQ * (NHEAD + NKV) * 64;
  rope_kernel<<<rope_threads / 256, 256, 0, stream>>>(qb, kvb);
  attn_mfma<<<BATCH * NHEAD * (TSEQ / QT), 256, 0, stream>>>(qb, kvb, yb, seq);
  gemm_mfma_bt<<<dim3(CDIM / 128, M / 128), 256, 0, stream>>>(yb, woT, d_out, M, CDIM, CDIM, flag);
}